// Round 1
// baseline (272.687 us; speedup 1.0000x reference)
//
#include <hip/hip_runtime.h>
#include <hip/hip_bf16.h>
#include <cstdint>
#include <cstddef>

typedef __bf16 bf16x8 __attribute__((ext_vector_type(8)));
typedef float  f32x4  __attribute__((ext_vector_type(4)));

constexpr int Bc = 2, Nc = 2048, Dc = 1024, Hc = 16, DHc = 64;
constexpr int BN = Bc * Nc;     // 4096
constexpr int E3 = 3 * DHc;     // 192
constexpr int BH = Bc * Hc;     // 32

__device__ __forceinline__ f32x4 mfma16(bf16x8 a, bf16x8 b, f32x4 c) {
  return __builtin_amdgcn_mfma_f32_16x16x32_bf16(a, b, c, 0, 0, 0);
}

// ---------- conversions ----------
__global__ void cvt_x_kernel(const float* __restrict__ x, __bf16* __restrict__ xb) {
  int i = (blockIdx.x * 256 + threadIdx.x) * 4;
  float4 v = *(const float4*)(x + i);
  xb[i + 0] = (__bf16)v.x;
  xb[i + 1] = (__bf16)v.y;
  xb[i + 2] = (__bf16)v.z;
  xb[i + 3] = (__bf16)v.w;
}

// Wkqv [H][D][192] f32 -> wkt [H][192][D] bf16
__global__ void cvt_wkqvT_kernel(const float* __restrict__ w, __bf16* __restrict__ wt) {
  int idx = blockIdx.x * 256 + threadIdx.x;       // over H*D*192
  int e = idx % E3;
  int d = (idx / E3) % Dc;
  int h = idx / (E3 * Dc);
  wt[((size_t)h * E3 + e) * Dc + d] = (__bf16)w[idx];
}

// Wo [D][D] f32 -> wot [D][D] bf16 transposed
__global__ void cvt_woT_kernel(const float* __restrict__ w, __bf16* __restrict__ wt) {
  int idx = blockIdx.x * 256 + threadIdx.x;       // over D*D
  int e = idx % Dc;
  int d = idx / Dc;
  wt[(size_t)e * Dc + d] = (__bf16)w[idx];
}

// ---------- KQV projection GEMM ----------
// xb [4096][1024] bf16, wkt [16][192][1024] bf16, bkqv [16][192] f32
// out: kqv [3][32][2048][64] bf16 (nt selects k/q/v buffer)
__launch_bounds__(256)
__global__ void kqv_gemm_kernel(const __bf16* __restrict__ xb,
                                const __bf16* __restrict__ wkt,
                                const float* __restrict__ bkqv,
                                __bf16* __restrict__ kqv) {
  const int mt = blockIdx.x;   // 0..63
  const int nt = blockIdx.y;   // 0..2
  const int h  = blockIdx.z;   // 0..15
  __shared__ __align__(16) __bf16 Al[64][72];
  __shared__ __align__(16) __bf16 Bl[64][72];
  const int tid  = threadIdx.x;
  const int lane = tid & 63;
  const int w    = tid >> 6;
  const int fr   = lane & 15, fq = lane >> 4;
  const int m0   = mt * 64;
  const __bf16* wth = wkt + ((size_t)h * E3 + nt * 64) * Dc;
  f32x4 acc[4] = {};
  for (int k0 = 0; k0 < Dc; k0 += 64) {
    __syncthreads();
#pragma unroll
    for (int it = 0; it < 2; ++it) {
      int g = tid + it * 256;
      int r = g >> 3, c = (g & 7) * 8;
      *(bf16x8*)&Al[r][c] = *(const bf16x8*)&xb[(size_t)(m0 + r) * Dc + k0 + c];
      *(bf16x8*)&Bl[r][c] = *(const bf16x8*)&wth[(size_t)r * Dc + k0 + c];
    }
    __syncthreads();
    bf16x8 a0 = *(const bf16x8*)&Al[w * 16 + fr][8 * fq];
    bf16x8 a1 = *(const bf16x8*)&Al[w * 16 + fr][32 + 8 * fq];
#pragma unroll
    for (int c = 0; c < 4; ++c) {
      bf16x8 b0 = *(const bf16x8*)&Bl[c * 16 + fr][8 * fq];
      bf16x8 b1 = *(const bf16x8*)&Bl[c * 16 + fr][32 + 8 * fq];
      acc[c] = mfma16(a0, b0, acc[c]);
      acc[c] = mfma16(a1, b1, acc[c]);
    }
  }
#pragma unroll
  for (int c = 0; c < 4; ++c) {
#pragma unroll
    for (int i = 0; i < 4; ++i) {
      int m  = m0 + w * 16 + fq * 4 + i;
      int el = c * 16 + fr;                         // 0..63
      float v = acc[c][i] + bkqv[h * E3 + nt * 64 + el];
      int b = m >> 11, n = m & (Nc - 1);
      kqv[((size_t)nt * BH * Nc + ((size_t)(b * Hc + h)) * Nc + n) * DHc + el] = (__bf16)v;
    }
  }
}

// ---------- flash attention (Q-role = k buffer, K-role = q buffer) ----------
// kb/qb/vb: [32][2048][64] bf16 ; sab out: [B][N][1024] bf16 (head-concat)
__launch_bounds__(256)
__global__ void attn_kernel(const __bf16* __restrict__ kb,
                            const __bf16* __restrict__ qb,
                            const __bf16* __restrict__ vb,
                            __bf16* __restrict__ sab) {
  const int qt = blockIdx.x;   // 0..31 (row tile)
  const int bh = blockIdx.y;   // 0..31
  __shared__ __align__(16) __bf16 Kq[64][72];     // K-role tile [kv][dh]
  __shared__ __align__(16) __bf16 Vt[64][72];     // V transposed [dh][kv]
  __shared__ __align__(16) __bf16 Pl[4][16][72];  // per-wave P
  const int tid  = threadIdx.x;
  const int lane = tid & 63;
  const int w    = tid >> 6;
  const int fr   = lane & 15, fq = lane >> 4;
  const int r0   = qt * 64 + w * 16;
  const __bf16* kbh = kb + (size_t)bh * Nc * DHc;
  const __bf16* qbh = qb + (size_t)bh * Nc * DHc;
  const __bf16* vbh = vb + (size_t)bh * Nc * DHc;

  bf16x8 a0 = *(const bf16x8*)&kbh[(size_t)(r0 + fr) * DHc + 8 * fq];
  bf16x8 a1 = *(const bf16x8*)&kbh[(size_t)(r0 + fr) * DHc + 32 + 8 * fq];

  float mrow[4], lrow[4];
  f32x4 acc[4] = {};
#pragma unroll
  for (int i = 0; i < 4; ++i) { mrow[i] = -3.0e38f; lrow[i] = 0.f; }

  for (int t = 0; t <= qt; ++t) {
    const int v0 = t * 64;
    __syncthreads();
#pragma unroll
    for (int it = 0; it < 2; ++it) {
      int g = tid + it * 256;
      int r = g >> 3, c = (g & 7) * 8;
      *(bf16x8*)&Kq[r][c] = *(const bf16x8*)&qbh[(size_t)(v0 + r) * DHc + c];
      bf16x8 vv = *(const bf16x8*)&vbh[(size_t)(v0 + r) * DHc + c];
      const __bf16* pv = (const __bf16*)&vv;
#pragma unroll
      for (int j = 0; j < 8; ++j) Vt[c + j][r] = pv[j];
    }
    __syncthreads();

    f32x4 s[4];
#pragma unroll
    for (int c = 0; c < 4; ++c) {
      bf16x8 b0 = *(const bf16x8*)&Kq[c * 16 + fr][8 * fq];
      bf16x8 b1 = *(const bf16x8*)&Kq[c * 16 + fr][32 + 8 * fq];
      f32x4 z = {};
      z = mfma16(a0, b0, z);
      z = mfma16(a1, b1, z);
      s[c] = z;
    }
    const bool diag = (t == qt);
    float pm[4] = {-3.0e38f, -3.0e38f, -3.0e38f, -3.0e38f};
#pragma unroll
    for (int c = 0; c < 4; ++c)
#pragma unroll
      for (int i = 0; i < 4; ++i) {
        float v = s[c][i] * 0.125f;
        if (diag && (v0 + c * 16 + fr) > (r0 + fq * 4 + i)) v = -3.0e38f;
        s[c][i] = v;
        pm[i] = fmaxf(pm[i], v);
      }
#pragma unroll
    for (int off = 1; off < 16; off <<= 1)
#pragma unroll
      for (int i = 0; i < 4; ++i) pm[i] = fmaxf(pm[i], __shfl_xor(pm[i], off));
    float al[4], rs[4] = {0.f, 0.f, 0.f, 0.f};
#pragma unroll
    for (int i = 0; i < 4; ++i) {
      float mn = fmaxf(mrow[i], pm[i]);
      al[i] = __expf(mrow[i] - mn);
      mrow[i] = mn;
    }
#pragma unroll
    for (int c = 0; c < 4; ++c)
#pragma unroll
      for (int i = 0; i < 4; ++i) {
        float p = __expf(s[c][i] - mrow[i]);
        s[c][i] = p;
        rs[i] += p;
      }
#pragma unroll
    for (int off = 1; off < 16; off <<= 1)
#pragma unroll
      for (int i = 0; i < 4; ++i) rs[i] += __shfl_xor(rs[i], off);
#pragma unroll
    for (int i = 0; i < 4; ++i) lrow[i] = lrow[i] * al[i] + rs[i];
#pragma unroll
    for (int d = 0; d < 4; ++d)
#pragma unroll
      for (int i = 0; i < 4; ++i) acc[d][i] *= al[i];
    // write P (per-wave private region), then wait for LDS writes to land
#pragma unroll
    for (int c = 0; c < 4; ++c)
#pragma unroll
      for (int i = 0; i < 4; ++i) Pl[w][fq * 4 + i][c * 16 + fr] = (__bf16)s[c][i];
    asm volatile("s_waitcnt lgkmcnt(0)" ::: "memory");
    __builtin_amdgcn_sched_barrier(0);
#pragma unroll
    for (int d = 0; d < 4; ++d) {
#pragma unroll
      for (int ks = 0; ks < 2; ++ks) {
        bf16x8 ap = *(const bf16x8*)&Pl[w][fr][ks * 32 + 8 * fq];
        bf16x8 bv = *(const bf16x8*)&Vt[d * 16 + fr][ks * 32 + 8 * fq];
        acc[d] = mfma16(ap, bv, acc[d]);
      }
    }
  }
  const int b = bh >> 4, h = bh & 15;
#pragma unroll
  for (int d = 0; d < 4; ++d)
#pragma unroll
    for (int i = 0; i < 4; ++i) {
      float ov = acc[d][i] / lrow[i];
      int n = r0 + fq * 4 + i;
      sab[((size_t)(b * Nc + n)) * Dc + h * DHc + d * 16 + fr] = (__bf16)ov;
    }
}

// ---------- output projection GEMM ----------
// sab [4096][1024] bf16, wot [1024][1024] bf16 (transposed), bo [1024] f32 -> out f32
__launch_bounds__(256)
__global__ void out_gemm_kernel(const __bf16* __restrict__ sab,
                                const __bf16* __restrict__ wot,
                                const float* __restrict__ bo,
                                float* __restrict__ out) {
  const int mt = blockIdx.x;   // 0..63
  const int nt = blockIdx.y;   // 0..15
  __shared__ __align__(16) __bf16 Al[64][72];
  __shared__ __align__(16) __bf16 Bl[64][72];
  const int tid  = threadIdx.x;
  const int lane = tid & 63;
  const int w    = tid >> 6;
  const int fr   = lane & 15, fq = lane >> 4;
  const int m0   = mt * 64;
  const __bf16* wtn = wot + (size_t)nt * 64 * Dc;
  f32x4 acc[4] = {};
  for (int k0 = 0; k0 < Dc; k0 += 64) {
    __syncthreads();
#pragma unroll
    for (int it = 0; it < 2; ++it) {
      int g = tid + it * 256;
      int r = g >> 3, c = (g & 7) * 8;
      *(bf16x8*)&Al[r][c] = *(const bf16x8*)&sab[(size_t)(m0 + r) * Dc + k0 + c];
      *(bf16x8*)&Bl[r][c] = *(const bf16x8*)&wtn[(size_t)r * Dc + k0 + c];
    }
    __syncthreads();
    bf16x8 a0 = *(const bf16x8*)&Al[w * 16 + fr][8 * fq];
    bf16x8 a1 = *(const bf16x8*)&Al[w * 16 + fr][32 + 8 * fq];
#pragma unroll
    for (int c = 0; c < 4; ++c) {
      bf16x8 b0 = *(const bf16x8*)&Bl[c * 16 + fr][8 * fq];
      bf16x8 b1 = *(const bf16x8*)&Bl[c * 16 + fr][32 + 8 * fq];
      acc[c] = mfma16(a0, b0, acc[c]);
      acc[c] = mfma16(a1, b1, acc[c]);
    }
  }
#pragma unroll
  for (int c = 0; c < 4; ++c)
#pragma unroll
    for (int i = 0; i < 4; ++i) {
      int m  = m0 + w * 16 + fq * 4 + i;
      int e  = nt * 64 + c * 16 + fr;
      out[(size_t)m * Dc + e] = acc[c][i] + bo[e];
    }
}

extern "C" void kernel_launch(void* const* d_in, const int* in_sizes, int n_in,
                              void* d_out, int out_size, void* d_ws, size_t ws_size,
                              hipStream_t stream) {
  const float* x    = (const float*)d_in[0];   // [2][2048][1024]
  const float* Wkqv = (const float*)d_in[1];   // [16][1024][192]
  const float* bkqv = (const float*)d_in[2];   // [16][192]
  const float* Wo   = (const float*)d_in[3];   // [1024][1024]
  const float* bo   = (const float*)d_in[4];   // [1024]
  float* out = (float*)d_out;                  // [2][2048][1024]

  __bf16* xb   = (__bf16*)d_ws;                        // 4096*1024
  __bf16* wkt  = xb  + (size_t)BN * Dc;                // 16*192*1024
  __bf16* wot  = wkt + (size_t)Hc * E3 * Dc;           // 1024*1024
  __bf16* kqv  = wot + (size_t)Dc * Dc;                // 3 * 32*2048*64
  __bf16* kbuf = kqv;
  __bf16* qbuf = kqv + (size_t)BH * Nc * DHc;
  __bf16* vbuf = kqv + 2 * (size_t)BH * Nc * DHc;
  __bf16* sab  = kqv + 3 * (size_t)BH * Nc * DHc;      // 4096*1024

  cvt_x_kernel<<<(BN * Dc) / (256 * 4), 256, 0, stream>>>(x, xb);
  cvt_wkqvT_kernel<<<(Hc * Dc * E3) / 256, 256, 0, stream>>>(Wkqv, wkt);
  cvt_woT_kernel<<<(Dc * Dc) / 256, 256, 0, stream>>>(Wo, wot);

  kqv_gemm_kernel<<<dim3(BN / 64, 3, Hc), 256, 0, stream>>>(xb, wkt, bkqv, kqv);

  attn_kernel<<<dim3(Nc / 64, BH), 256, 0, stream>>>(kbuf, qbuf, vbuf, sab);

  out_gemm_kernel<<<dim3(BN / 64, Dc / 64), 256, 0, stream>>>(sab, wot, bo, out);
}

// Round 2
// 139.250 us; speedup vs baseline: 1.9583x; 1.9583x over previous
//
#include <hip/hip_runtime.h>
#include <hip/hip_bf16.h>
#include <cstdint>
#include <cstddef>

typedef __bf16 bf16x8 __attribute__((ext_vector_type(8)));
typedef __bf16 bf16x4 __attribute__((ext_vector_type(4)));
typedef float  f32x4  __attribute__((ext_vector_type(4)));

constexpr int Bc = 2, Nc = 2048, Dc = 1024, Hc = 16, DHc = 64;
constexpr int BN = Bc * Nc;     // 4096
constexpr int E3 = 3 * DHc;     // 192
constexpr int BH = Bc * Hc;     // 32

__device__ __forceinline__ f32x4 mfma16(bf16x8 a, bf16x8 b, f32x4 c) {
  return __builtin_amdgcn_mfma_f32_16x16x32_bf16(a, b, c, 0, 0, 0);
}

// ---------- conversions ----------
__global__ void cvt_x_kernel(const float* __restrict__ x, __bf16* __restrict__ xb) {
  int i = (blockIdx.x * 256 + threadIdx.x) * 4;
  float4 v = *(const float4*)(x + i);
  xb[i + 0] = (__bf16)v.x;
  xb[i + 1] = (__bf16)v.y;
  xb[i + 2] = (__bf16)v.z;
  xb[i + 3] = (__bf16)v.w;
}

// Transpose-convert: src f32 [slice][R][C] -> dst bf16 [slice][C][R], 64x64 tiles.
constexpr int TP = 68;  // pad: 4-row store stride = 544B -> 4-way (free-ish); rows 8B-aligned
__global__ void cvt_T_kernel(const float* __restrict__ src, __bf16* __restrict__ dst,
                             int R, int C) {
  __shared__ __bf16 T[64][TP];
  const int c0 = blockIdx.x * 64, r0 = blockIdx.y * 64;
  const size_t sbase = (size_t)blockIdx.z * R * C;
  const int tid = threadIdx.x;
#pragma unroll
  for (int it = 0; it < 4; ++it) {
    int g = tid + it * 256;
    int r = g >> 4, c4 = (g & 15) * 4;
    float4 v = *(const float4*)&src[sbase + (size_t)(r0 + r) * C + c0 + c4];
    T[c4 + 0][r] = (__bf16)v.x;
    T[c4 + 1][r] = (__bf16)v.y;
    T[c4 + 2][r] = (__bf16)v.z;
    T[c4 + 3][r] = (__bf16)v.w;
  }
  __syncthreads();
#pragma unroll
  for (int it = 0; it < 2; ++it) {
    int g = tid + it * 256;
    int c = g >> 3, ch = (g & 7) * 8;
    bf16x4 u0 = *(const bf16x4*)&T[c][ch];
    bf16x4 u1 = *(const bf16x4*)&T[c][ch + 4];
    __bf16* dp = &dst[sbase + (size_t)(c0 + c) * R + r0 + ch];
    *(bf16x4*)dp = u0;
    *(bf16x4*)(dp + 4) = u1;
  }
}

// ---------- KQV projection GEMM ----------
// xb [4096][1024], wkt [16][192][1024], bkqv [16][192] f32
// outputs: kq buffers [2][32][2048][64] (k pre-scaled by 0.125), vT [32][64][2048]
__launch_bounds__(256)
__global__ void kqv_gemm_kernel(const __bf16* __restrict__ xb,
                                const __bf16* __restrict__ wkt,
                                const float* __restrict__ bkqv,
                                __bf16* __restrict__ kqv,
                                __bf16* __restrict__ vT) {
  const int mt = blockIdx.x;   // 0..63
  const int nt = blockIdx.y;   // 0..2
  const int h  = blockIdx.z;   // 0..15
  __shared__ __align__(16) __bf16 Al[64][72];
  __shared__ __align__(16) __bf16 Bl[64][72];
  const int tid  = threadIdx.x;
  const int lane = tid & 63;
  const int w    = tid >> 6;
  const int fr   = lane & 15, fq = lane >> 4;
  const int m0   = mt * 64;
  const __bf16* wth = wkt + ((size_t)h * E3 + nt * 64) * Dc;
  f32x4 acc[4] = {};
  for (int k0 = 0; k0 < Dc; k0 += 64) {
    __syncthreads();
#pragma unroll
    for (int it = 0; it < 2; ++it) {
      int g = tid + it * 256;
      int r = g >> 3, c = (g & 7) * 8;
      *(bf16x8*)&Al[r][c] = *(const bf16x8*)&xb[(size_t)(m0 + r) * Dc + k0 + c];
      *(bf16x8*)&Bl[r][c] = *(const bf16x8*)&wth[(size_t)r * Dc + k0 + c];
    }
    __syncthreads();
    bf16x8 a0 = *(const bf16x8*)&Al[w * 16 + fr][8 * fq];
    bf16x8 a1 = *(const bf16x8*)&Al[w * 16 + fr][32 + 8 * fq];
#pragma unroll
    for (int c = 0; c < 4; ++c) {
      bf16x8 b0 = *(const bf16x8*)&Bl[c * 16 + fr][8 * fq];
      bf16x8 b1 = *(const bf16x8*)&Bl[c * 16 + fr][32 + 8 * fq];
      acc[c] = mfma16(a0, b0, acc[c]);
      acc[c] = mfma16(a1, b1, acc[c]);
    }
  }
  const int b = m0 >> 11;                 // batch (tile never crosses)
  if (nt == 2) {
    // V transposed: vT[(b*H+h)][el][n]
    const int nn0 = (m0 & (Nc - 1)) + w * 16 + fq * 4;
#pragma unroll
    for (int c = 0; c < 4; ++c) {
      int el = c * 16 + fr;
      float bv = bkqv[h * E3 + 128 + el];
      bf16x4 v4;
#pragma unroll
      for (int i = 0; i < 4; ++i) v4[i] = (__bf16)(acc[c][i] + bv);
      *(bf16x4*)&vT[((size_t)((b * Hc + h) * DHc + el)) * Nc + nn0] = v4;
    }
  } else {
    const float sc = (nt == 0) ? 0.125f : 1.0f;   // pre-scale k (Q-role) by 1/sqrt(dh)
#pragma unroll
    for (int c = 0; c < 4; ++c) {
#pragma unroll
      for (int i = 0; i < 4; ++i) {
        int m  = m0 + w * 16 + fq * 4 + i;
        int el = c * 16 + fr;
        float v = (acc[c][i] + bkqv[h * E3 + nt * 64 + el]) * sc;
        int n = m & (Nc - 1);
        kqv[((size_t)nt * BH * Nc + ((size_t)(b * Hc + h)) * Nc + n) * DHc + el] = (__bf16)v;
      }
    }
  }
}

// ---------- flash attention, S^T orientation ----------
// kb (Q-role, pre-scaled), qb (K-role): [32][2048][64]; vT: [32][64][2048]
// sab out: [B][N][1024] bf16 (head-concat)
__launch_bounds__(256)
__global__ void attn_kernel(const __bf16* __restrict__ kb,
                            const __bf16* __restrict__ qb,
                            const __bf16* __restrict__ vT,
                            __bf16* __restrict__ sab) {
  const int pair = blockIdx.x;  // 0..15 -> handles qt=pair and qt=31-pair
  const int bh   = blockIdx.y;  // 0..31
  __shared__ __align__(16) __bf16 Kq[64][72];     // K-role tile [kv][dh]
  __shared__ __align__(16) __bf16 Vt[64][72];     // V^T tile [dh][kv]
  __shared__ __align__(16) __bf16 Pl[4][16][72];  // per-wave P [n-local][kv]
  const int tid  = threadIdx.x;
  const int lane = tid & 63;
  const int w    = tid >> 6;
  const int fr   = lane & 15, fq = lane >> 4;
  const int fq4  = fq * 4;
  const __bf16* kbh = kb + (size_t)bh * Nc * DHc;
  const __bf16* qbh = qb + (size_t)bh * Nc * DHc;
  const __bf16* vth = vT + (size_t)bh * DHc * Nc;
  __bf16 (*Plw)[72] = Pl[w];
  const int b = bh >> 4, h = bh & 15;

  for (int ph = 0; ph < 2; ++ph) {
    const int qt = ph ? (Nc / 64 - 1 - pair) : pair;
    const int n0 = qt * 64 + w * 16;      // this wave's 16 q-rows
    const int ncol = n0 + fr;             // this lane's softmax column (q row)
    // Q-role fragment (B operand): lane fr holds row n0+fr, 8 contig d at 8*fq
    bf16x8 bq0 = *(const bf16x8*)&kbh[(size_t)(n0 + fr) * DHc + 8 * fq];
    bf16x8 bq1 = *(const bf16x8*)&kbh[(size_t)(n0 + fr) * DHc + 32 + 8 * fq];

    float m_run = -3.0e38f, l_run = 0.f;
    f32x4 acc[4] = {};

    for (int t = 0; t <= qt; ++t) {
      const int v0 = t * 64;
      __syncthreads();
#pragma unroll
      for (int it = 0; it < 2; ++it) {
        int g = tid + it * 256;
        int r = g >> 3, c = (g & 7) * 8;
        *(bf16x8*)&Kq[r][c] = *(const bf16x8*)&qbh[(size_t)(v0 + r) * DHc + c];
        *(bf16x8*)&Vt[r][c] = *(const bf16x8*)&vth[(size_t)r * Nc + v0 + c];
      }
      __syncthreads();

      // S^T[m][n]: A = Kq tile rows (m), B = per-thread Q-role regs (n)
      f32x4 s[4];
      __builtin_amdgcn_s_setprio(1);
#pragma unroll
      for (int c = 0; c < 4; ++c) {
        bf16x8 t0 = *(const bf16x8*)&Kq[c * 16 + fr][8 * fq];
        bf16x8 t1 = *(const bf16x8*)&Kq[c * 16 + fr][32 + 8 * fq];
        f32x4 z = {};
        z = mfma16(t0, bq0, z);
        z = mfma16(t1, bq1, z);
        s[c] = z;
      }
      __builtin_amdgcn_s_setprio(0);

      // mask (diag tile only) + tile max, in-lane over 16 values
      float pm = -3.0e38f;
      if (t == qt) {
        const int thr = ncol - v0;   // keep m-local <= thr
#pragma unroll
        for (int c = 0; c < 4; ++c)
#pragma unroll
          for (int i = 0; i < 4; ++i) {
            float v = (c * 16 + fq4 + i > thr) ? -3.0e38f : s[c][i];
            s[c][i] = v;
            pm = fmaxf(pm, v);
          }
      } else {
#pragma unroll
        for (int c = 0; c < 4; ++c)
#pragma unroll
          for (int i = 0; i < 4; ++i) pm = fmaxf(pm, s[c][i]);
      }
      pm = fmaxf(pm, __shfl_xor(pm, 16));
      pm = fmaxf(pm, __shfl_xor(pm, 32));
      const float mn = fmaxf(m_run, pm);
      const float al = __expf(m_run - mn);
      m_run = mn;
      float rs = 0.f;
#pragma unroll
      for (int c = 0; c < 4; ++c)
#pragma unroll
        for (int i = 0; i < 4; ++i) {
          float p = __expf(s[c][i] - mn);
          s[c][i] = p;
          rs += p;
        }
      rs += __shfl_xor(rs, 16);
      rs += __shfl_xor(rs, 32);
      l_run = l_run * al + rs;

      // redistribute rescale factor to acc rows (acc row n-local = fq*4+ii)
      float alv[4];
#pragma unroll
      for (int ii = 0; ii < 4; ++ii) alv[ii] = __shfl(al, fq4 + ii);
#pragma unroll
      for (int d = 0; d < 4; ++d)
#pragma unroll
        for (int ii = 0; ii < 4; ++ii) acc[d][ii] *= alv[ii];

      // store P[n-local][m-local] packed (4x ds_write_b64)
#pragma unroll
      for (int c = 0; c < 4; ++c) {
        bf16x4 p4;
#pragma unroll
        for (int i = 0; i < 4; ++i) p4[i] = (__bf16)s[c][i];
        *(bf16x4*)&Plw[fr][c * 16 + fq4] = p4;
      }
      asm volatile("s_waitcnt lgkmcnt(0)" ::: "memory");
      __builtin_amdgcn_sched_barrier(0);

      // PV: A = P rows (n), B = Vt rows (d as cols), contract over m
      __builtin_amdgcn_s_setprio(1);
#pragma unroll
      for (int d = 0; d < 4; ++d) {
#pragma unroll
        for (int ks = 0; ks < 2; ++ks) {
          bf16x8 ap = *(const bf16x8*)&Plw[fr][ks * 32 + 8 * fq];
          bf16x8 bv = *(const bf16x8*)&Vt[d * 16 + fr][ks * 32 + 8 * fq];
          acc[d] = mfma16(ap, bv, acc[d]);
        }
      }
      __builtin_amdgcn_s_setprio(0);
    }

    // epilogue: acc[d][ii] = out[n0+fq*4+ii][d*16+fr]
    float linv[4];
#pragma unroll
    for (int ii = 0; ii < 4; ++ii) linv[ii] = 1.0f / __shfl(l_run, fq4 + ii);
#pragma unroll
    for (int d = 0; d < 4; ++d)
#pragma unroll
      for (int ii = 0; ii < 4; ++ii) {
        int n  = n0 + fq4 + ii;
        int dd = d * 16 + fr;
        sab[((size_t)(b * Nc + n)) * Dc + h * DHc + dd] = (__bf16)(acc[d][ii] * linv[ii]);
      }
  }
}

// ---------- output projection GEMM ----------
__launch_bounds__(256)
__global__ void out_gemm_kernel(const __bf16* __restrict__ sab,
                                const __bf16* __restrict__ wot,
                                const float* __restrict__ bo,
                                float* __restrict__ out) {
  const int mt = blockIdx.x;   // 0..63
  const int nt = blockIdx.y;   // 0..15
  __shared__ __align__(16) __bf16 Al[64][72];
  __shared__ __align__(16) __bf16 Bl[64][72];
  const int tid  = threadIdx.x;
  const int lane = tid & 63;
  const int w    = tid >> 6;
  const int fr   = lane & 15, fq = lane >> 4;
  const int m0   = mt * 64;
  const __bf16* wtn = wot + (size_t)nt * 64 * Dc;
  f32x4 acc[4] = {};
  for (int k0 = 0; k0 < Dc; k0 += 64) {
    __syncthreads();
#pragma unroll
    for (int it = 0; it < 2; ++it) {
      int g = tid + it * 256;
      int r = g >> 3, c = (g & 7) * 8;
      *(bf16x8*)&Al[r][c] = *(const bf16x8*)&sab[(size_t)(m0 + r) * Dc + k0 + c];
      *(bf16x8*)&Bl[r][c] = *(const bf16x8*)&wtn[(size_t)r * Dc + k0 + c];
    }
    __syncthreads();
    bf16x8 a0 = *(const bf16x8*)&Al[w * 16 + fr][8 * fq];
    bf16x8 a1 = *(const bf16x8*)&Al[w * 16 + fr][32 + 8 * fq];
#pragma unroll
    for (int c = 0; c < 4; ++c) {
      bf16x8 b0 = *(const bf16x8*)&Bl[c * 16 + fr][8 * fq];
      bf16x8 b1 = *(const bf16x8*)&Bl[c * 16 + fr][32 + 8 * fq];
      acc[c] = mfma16(a0, b0, acc[c]);
      acc[c] = mfma16(a1, b1, acc[c]);
    }
  }
#pragma unroll
  for (int c = 0; c < 4; ++c)
#pragma unroll
    for (int i = 0; i < 4; ++i) {
      int m = m0 + w * 16 + fq * 4 + i;
      int e = nt * 64 + c * 16 + fr;
      out[(size_t)m * Dc + e] = acc[c][i] + bo[e];
    }
}

extern "C" void kernel_launch(void* const* d_in, const int* in_sizes, int n_in,
                              void* d_out, int out_size, void* d_ws, size_t ws_size,
                              hipStream_t stream) {
  const float* x    = (const float*)d_in[0];   // [2][2048][1024]
  const float* Wkqv = (const float*)d_in[1];   // [16][1024][192]
  const float* bkqv = (const float*)d_in[2];   // [16][192]
  const float* Wo   = (const float*)d_in[3];   // [1024][1024]
  const float* bo   = (const float*)d_in[4];   // [1024]
  float* out = (float*)d_out;                  // [2][2048][1024]

  __bf16* xb   = (__bf16*)d_ws;                        // 4096*1024
  __bf16* wkt  = xb  + (size_t)BN * Dc;                // 16*192*1024
  __bf16* wot  = wkt + (size_t)Hc * E3 * Dc;           // 1024*1024
  __bf16* kqv  = wot + (size_t)Dc * Dc;                // 3 * 32*2048*64
  __bf16* kbuf = kqv;                                  // Q-role (pre-scaled)
  __bf16* qbuf = kqv + (size_t)BH * Nc * DHc;          // K-role
  __bf16* vTb  = kqv + 2 * (size_t)BH * Nc * DHc;      // [32][64][2048]
  __bf16* sab  = kqv + 3 * (size_t)BH * Nc * DHc;      // 4096*1024

  cvt_x_kernel<<<(BN * Dc) / (256 * 4), 256, 0, stream>>>(x, xb);
  // Wkqv: slices=16, R=1024, C=192 -> wkt [16][192][1024]
  cvt_T_kernel<<<dim3(E3 / 64, Dc / 64, Hc), 256, 0, stream>>>(Wkqv, wkt, Dc, E3);
  // Wo: R=C=1024 -> wot [1024][1024] (transposed)
  cvt_T_kernel<<<dim3(Dc / 64, Dc / 64, 1), 256, 0, stream>>>(Wo, wot, Dc, Dc);

  kqv_gemm_kernel<<<dim3(BN / 64, 3, Hc), 256, 0, stream>>>(xb, wkt, bkqv, kqv, vTb);

  attn_kernel<<<dim3(Nc / 128, BH), 256, 0, stream>>>(kbuf, qbuf, vTb, sab);

  out_gemm_kernel<<<dim3(BN / 64, Dc / 64), 256, 0, stream>>>(sab, wot, bo, out);
}